// Round 15
// baseline (1671.027 us; speedup 1.0000x reference)
//
#include <hip/hip_runtime.h>
#include <hip/hip_bf16.h>
#include <stdint.h>

// Problem constants
#define TT 256
#define BH 65536        // B*H
#define B4H 262144      // B*4H
#define OUT_HL 16777216
#define OUT_CL (16777216 + 131072)
#define NBLK 256
#define SLAB 65536      // ushorts per [64][1024] bf16 activation slab

typedef __attribute__((ext_vector_type(8))) short bf16x8;
typedef __attribute__((ext_vector_type(4))) float f32x4;
typedef __attribute__((ext_vector_type(4))) unsigned int u32x4;
typedef __attribute__((ext_vector_type(2))) unsigned int u32x2;

__device__ __forceinline__ ushort f2bf(float v) {
    union { float f; uint32_t u; } x; x.f = v;
    uint32_t r = x.u + 0x7fff + ((x.u >> 16) & 1);
    return (ushort)(r >> 16);
}
__device__ __forceinline__ float sigf(float x) { return 1.f / (1.f + __expf(-x)); }

// Fragment-major layout for [64][1024] bf16 activation slabs:
//   off(b,k) = (b>>4)*16384 + (k>>5)*512 + ((k>>3)&3)*128 + (b&15)*8 + (k&7)

// Build Wt[l][col'][k] bf16, col' = u*4+g for source column col=g*1024+u.
// sc stores: region is later reused as the layer-1 h ring (plain cached reads).
__global__ __launch_bounds__(256) void k_prep_wt(const float* __restrict__ wih,
                                                 const float* __restrict__ whh,
                                                 ushort* __restrict__ Wt) {
    __shared__ ushort tile[64][65];
    const int l = blockIdx.z;
    const int k0 = blockIdx.x * 64;
    const int col0 = blockIdx.y * 64;
    const int tid = threadIdx.x;
    const int cl = tid & 63, ks = tid >> 6;
    const float* src;
    int krow0;
    if (k0 < 1024) { src = wih + (size_t)l * 1024 * 4096; krow0 = k0; }
    else           { src = whh + (size_t)l * 1024 * 4096; krow0 = k0 - 1024; }
#pragma unroll
    for (int i = 0; i < 16; ++i) {
        int kl = ks + i * 4;
        tile[kl][cl] = f2bf(src[(size_t)(krow0 + kl) * 4096 + col0 + cl]);
    }
    __syncthreads();
    const int g0 = col0 >> 10, ub = col0 & 1023;
    ushort* dst = Wt + (size_t)l * 4096 * 2048;
    const int klane = tid & 63;
#pragma unroll
    for (int i = 0; i < 16; ++i) {
        int cl2 = (tid >> 6) + i * 4;
        int row = (ub + cl2) * 4 + g0;
        ushort* p = dst + (size_t)row * 2048 + k0 + klane;
        uint v = (uint)tile[klane][cl2];
        asm volatile("global_store_short %0, %1, off sc0 sc1"
                     :: "v"(p), "v"(v) : "memory");
    }
}

// x -> bf16 fragment-major xbfF[t][...]
__global__ __launch_bounds__(256) void k_cast_x(const float* __restrict__ x,
                                                ushort* __restrict__ xbfF) {
    int i = blockIdx.x * 256 + threadIdx.x;   // [256 t][64 b][128 k8]
    int k8 = i & 127, b = (i >> 7) & 63, t = i >> 13;
    const float4* xs = (const float4*)(x + (((size_t)t * 64 + b) * 1024 + k8 * 8));
    float4 a = xs[0], c = xs[1];
    uint4 pk;
    pk.x = (uint)f2bf(a.x) | ((uint)f2bf(a.y) << 16);
    pk.y = (uint)f2bf(a.z) | ((uint)f2bf(a.w) << 16);
    pk.z = (uint)f2bf(c.x) | ((uint)f2bf(c.y) << 16);
    pk.w = (uint)f2bf(c.z) | ((uint)f2bf(c.w) << 16);
    size_t off = (size_t)t * SLAB + (size_t)(b >> 4) * 16384 +
                 (size_t)(k8 >> 2) * 512 + (size_t)(k8 & 3) * 128 + (size_t)(b & 15) * 8;
    *(uint4*)(xbfF + off) = pk;
}

// const[l][b][col] = a0[b,:] @ W_ah[l][:,col] + bias_ah + bias_ih + bias_hh
__global__ __launch_bounds__(256) void k_const(const float* __restrict__ attn,
                                               const float* __restrict__ wah,
                                               const float* __restrict__ bah,
                                               const float* __restrict__ bih,
                                               const float* __restrict__ bhh,
                                               float* __restrict__ constg) {
    const int tid = threadIdx.x;
    const int col = blockIdx.x * 256 + tid;
    const int b0 = blockIdx.y * 8;
    const int l = blockIdx.z;
    const float* W = wah + (size_t)l * 512 * 4096;
    float acc[8] = {0.f, 0.f, 0.f, 0.f, 0.f, 0.f, 0.f, 0.f};
    for (int k = 0; k < 512; ++k) {
        float wv = W[(size_t)k * 4096 + col];
#pragma unroll
        for (int j = 0; j < 8; ++j) acc[j] += attn[(b0 + j) * 512 + k] * wv;
    }
    float bias = bah[l * 4096 + col] + bih[l * 4096 + col] + bhh[l * 4096 + col];
    float* cg = constg + (size_t)l * B4H;
#pragma unroll
    for (int j = 0; j < 8; ++j) cg[(size_t)(b0 + j) * 4096 + col] = acc[j] + bias;
}

// h0 -> fragment-major initial slabs; zero flags
__global__ __launch_bounds__(256) void k_init(const float* __restrict__ h0,
                                              ushort* __restrict__ hs0F,
                                              ushort* __restrict__ h1s0,
                                              unsigned* __restrict__ flags) {
    int i = blockIdx.x * 256 + threadIdx.x;   // [2 l][64 b][128 k8] = 16384
    if (i < 16384) {
        int k8 = i & 127, b = (i >> 7) & 63, l = i >> 13;
        const float* src = h0 + ((size_t)(l * 64 + b) * 1024 + k8 * 8);
        uint4 pk;
        pk.x = (uint)f2bf(src[0]) | ((uint)f2bf(src[1]) << 16);
        pk.y = (uint)f2bf(src[2]) | ((uint)f2bf(src[3]) << 16);
        pk.z = (uint)f2bf(src[4]) | ((uint)f2bf(src[5]) << 16);
        pk.w = (uint)f2bf(src[6]) | ((uint)f2bf(src[7]) << 16);
        size_t off = (size_t)(b >> 4) * 16384 + (size_t)(k8 >> 2) * 512 +
                     (size_t)(k8 & 3) * 128 + (size_t)(b & 15) * 8;
        *(uint4*)((l == 0 ? hs0F : h1s0) + off) = pk;
    }
    if (i < NBLK) flags[i] = 0u;
}

// ---- inline-asm helpers ----
#define ISSUE(BUF, BASE)                                                       \
    do { _Pragma("unroll")                                                     \
        for (int _i = 0; _i < 8; ++_i)                                         \
            asm volatile("global_load_dwordx4 %0, %1, off"                     \
                         : "=v"(BUF[_i]) : "v"((BASE) + _i * 512)); } while (0)

// Wait (N outstanding allowed), then 8 ktg x 2 nt = 16 MFMAs.
#define CHUNK(BUF, KTG0, N, A0, A1)                                            \
    do {                                                                       \
        asm volatile("s_waitcnt vmcnt(" #N ")" ::: "memory");                  \
        __builtin_amdgcn_sched_barrier(0x100);                                 \
        _Pragma("unroll")                                                      \
        for (int _i = 0; _i < 8; ++_i) {                                       \
            int _ktg = (KTG0) + _i;                                            \
            bf16x8 _b0 = *(const bf16x8*)(wlds + (size_t)_ktg * 1024 + lane * 8);       \
            bf16x8 _b1 = *(const bf16x8*)(wlds + (size_t)_ktg * 1024 + 512 + lane * 8); \
            A0 = __builtin_amdgcn_mfma_f32_16x16x32_bf16(BUF[_i], _b0, A0, 0, 0, 0);    \
            A1 = __builtin_amdgcn_mfma_f32_16x16x32_bf16(BUF[_i], _b1, A1, 0, 0, 0);    \
        }                                                                      \
    } while (0)

// 128-flag poll, single wave, 2 flags/lane.
#define POLL128(FB, TGT)                                                       \
    do {                                                                       \
        const unsigned* _fp = (FB) + lane * 2;                                 \
        while (true) {                                                         \
            u32x2 _f;                                                          \
            asm volatile("global_load_dwordx2 %0, %1, off sc0 sc1\n\t"         \
                         "s_waitcnt vmcnt(0)"                                  \
                         : "=v"(_f) : "v"(_fp) : "memory");                    \
            if (__all(_f.x >= (TGT) && _f.y >= (TGT))) break;                  \
            __builtin_amdgcn_s_sleep(1);                                       \
        }                                                                      \
    } while (0)

#define MBX_SET(I, V)                                                          \
    __hip_atomic_store(&mbx[I], (unsigned)(V), __ATOMIC_RELEASE,               \
                       __HIP_MEMORY_SCOPE_WORKGROUP)
#define MBX_SPIN(I, V)                                                         \
    while (__hip_atomic_load(&mbx[I], __ATOMIC_ACQUIRE,                        \
                             __HIP_MEMORY_SCOPE_WORKGROUP) < (unsigned)(V))    \
        __builtin_amdgcn_s_sleep(1)

// Persistent 2-layer LSTM, layer-split (r12 base + ONE change in L0).
// Blocks 0-127 = layer0 (8 units each), 128-255 = layer1.
// L0 iter s: x[s]-MFMA from carried regs (N=8/0; stall absorbed by poll
//   slack) -> poll f0 + barrier -> issue h[s] -> h-MFMA (8/0) -> merge ->
//   epilogue -> h-store -> ISSUE x[s+1] AFTER the store -> vmcnt(16)
//   (retires ONLY the store; x' loads stay in flight across the loop edge)
//   -> sync2 -> signal f0=s+1. The x-prefetch residual is thereby removed
//   from the f0 signal path, which paces the whole grid.
// L1 iter s (t=s-1) [r12-verbatim]: w0 polls f0 -> mbx0; w4 polls f1 -> mbx1
//   (concurrent). kh0 waves spin mbx0, ingest hs0F[s]; kh1 waves spin mbx1,
//   ingest ring[t-1]. merge -> epilogue -> ring[t] store -> drain -> signal
//   f1=s+1 -> out rows.
// Ring aliasing over Wt: slot t first written at iter t+1, gated by f0/f1
// chains proving all staging reads finished (same proof as r9/r12).
__global__ __launch_bounds__(512, 2) void k_persist(
        const ushort* __restrict__ xbfF,
        ushort* __restrict__ hs0F,
        const ushort* __restrict__ h1s0,
        ushort* Wt,                       // staging source + h1 ring (aliased)
        const float* __restrict__ constg,
        const float* __restrict__ c0,
        float* __restrict__ out,
        unsigned* __restrict__ flags) {
    __shared__ ushort wlds[65536];          // [64 ktg][2 nt][64 lane][8] = 128 KiB
    __shared__ float gt[2][4][2][16][18];   // [kh][m][nt][b&15][col'] 18 KiB
    __shared__ unsigned mbx[2];

    const int tid = threadIdx.x;
    const int w = tid >> 6, lane = tid & 63;
    const int kh = w >> 2, m = w & 3;
    const int bid = blockIdx.x;
    const int layer = bid >> 7, ub = bid & 127;
    const int u0g = ub * 8;

    // ---- stage this layer's 32 gate-cols x 2048 k into LDS (sc loads) ----
    {
        bf16x8 vst[16];
#pragma unroll
        for (int i = 0; i < 16; ++i) {
            int c = i * 512 + tid;
            int lp = c & 63, nt = (c >> 6) & 1, ktg = c >> 7;
            int colp = u0g * 4 + nt * 16 + (lp & 15);
            int kk = ktg * 32 + (lp >> 4) * 8;
            const ushort* src = Wt + ((size_t)(layer * 4096 + colp)) * 2048 + kk;
            asm volatile("global_load_dwordx4 %0, %1, off sc0 sc1"
                         : "=v"(vst[i]) : "v"(src));
        }
        asm volatile("s_waitcnt vmcnt(0)" ::: "memory");
        __builtin_amdgcn_sched_barrier(0);
#pragma unroll
        for (int i = 0; i < 16; ++i) {
            int c = i * 512 + tid;
            *(bf16x8*)(wlds + (size_t)c * 8) = vst[i];
        }
    }
    if (tid == 0) { mbx[0] = 0u; mbx[1] = 0u; }

    const int b_e = (w << 3) | (lane >> 3);
    const int u_off = lane & 7;
    const int u_e = u0g + u_off;
    float cg[4];
#pragma unroll
    for (int g = 0; g < 4; ++g)
        cg[g] = constg[(size_t)layer * B4H + (size_t)b_e * 4096 + g * 1024 + u_e];
    float creg = c0[layer * BH + b_e * 1024 + u_e];
    const int mb = b_e >> 4, blb = b_e & 15, ntb = u_off >> 2, cpb = (u_off & 3) * 4;
    const size_t hoffL = (size_t)mb * 16384 + (size_t)(ub >> 2) * 512 +
                         (size_t)(ub & 3) * 128 + (size_t)blb * 8;

    const size_t fro = (size_t)m * 16384 + (size_t)lane * 8;
    unsigned* f0 = flags;
    unsigned* f1 = flags + 128;

    __syncthreads();

    if (layer == 0) {
        bf16x8 bufXa[8], bufXb[8];
        // prologue: load x[0], complete (landed regs are safe to carry)
        {
            const ushort* ax = xbfF + fro + kh * 8192;
            ISSUE(bufXa, ax); ISSUE(bufXb, ax + 4096);
            asm volatile("s_waitcnt vmcnt(0)" ::: "memory");
            __builtin_amdgcn_sched_barrier(0);
        }
        for (int s = 0; s < TT; ++s) {
            f32x4 aE0 = {0,0,0,0}, aO0 = {0,0,0,0};
            f32x4 aE1 = {0,0,0,0}, aO1 = {0,0,0,0};
            bf16x8 bufHa[8], bufHb[8];
            // 1) x[s] MFMA; carried loads (16 outstanding for s>=1) retire at
            //    8/0. Any residual stall here is absorbed by the step-2 poll.
            CHUNK(bufXa, kh * 16,     8, aE0, aE1);
            CHUNK(bufXb, kh * 16 + 8, 0, aO0, aO1);
            // 2) poll own-layer peers (their iter s-1) + release
            if (s >= 1 && w == 0) POLL128(f0, (unsigned)s);
            __syncthreads();
            // 3) h[s] ingest + h MFMA (h-only in flight: 8/0)
            {
                const ushort* ah = hs0F + (size_t)s * SLAB + fro + kh * 8192;
                ISSUE(bufHa, ah); ISSUE(bufHb, ah + 4096);          // 16 out
                CHUNK(bufHa, 32 + kh * 16,     8, aE0, aE1);
                CHUNK(bufHb, 32 + kh * 16 + 8, 0, aO0, aO1);
            }
            // 4) merge partials
            {
                const int cc = lane & 15, r0 = (lane >> 4) * 4;
#pragma unroll
                for (int r = 0; r < 4; ++r) {
                    gt[kh][m][0][r0 + r][cc] = aE0[r] + aO0[r];
                    gt[kh][m][1][r0 + r][cc] = aE1[r] + aO1[r];
                }
            }
            __syncthreads();                              // sync1
            // 5) balanced cell epilogue
            float g4[4];
#pragma unroll
            for (int g = 0; g < 4; ++g)
                g4[g] = gt[0][mb][ntb][blb][cpb + g] + gt[1][mb][ntb][blb][cpb + g] + cg[g];
            float si = sigf(g4[0]), sf = sigf(g4[1]), so = sigf(g4[3]);
            float cn = sf * creg + si * (2.f * sigf(2.f * g4[2]) - 1.f);
            float hv = so * (2.f * sigf(2.f * cn) - 1.f);
            creg = cn;
            uint hb = (uint)f2bf(hv);
            uint p0 = __shfl(hb, (lane & 56) + 0), p1 = __shfl(hb, (lane & 56) + 1);
            uint p2 = __shfl(hb, (lane & 56) + 2), p3 = __shfl(hb, (lane & 56) + 3);
            uint p4 = __shfl(hb, (lane & 56) + 4), p5 = __shfl(hb, (lane & 56) + 5);
            uint p6 = __shfl(hb, (lane & 56) + 6), p7 = __shfl(hb, (lane & 56) + 7);
            u32x4 hp;
            hp.x = (p0 & 0xffffu) | (p1 << 16);
            hp.y = (p2 & 0xffffu) | (p3 << 16);
            hp.z = (p4 & 0xffffu) | (p5 << 16);
            hp.w = (p6 & 0xffffu) | (p7 << 16);
            ushort* hdst = hs0F + (size_t)(s + 1) * SLAB + hoffL;
            if (u_off == 0)
                asm volatile("global_store_dwordx4 %0, %1, off sc0 sc1"
                             :: "v"(hdst), "v"(hp) : "memory");
            // 6) issue x[s+1] AFTER the store (store is oldest), drain ONLY
            //    the store via vmcnt(16); x' loads fly across the loop edge.
            {
                const ushort* ax = xbfF + (size_t)((s + 1) & 255) * SLAB + fro + kh * 8192;
                ISSUE(bufXa, ax); ISSUE(bufXb, ax + 4096);
            }
            asm volatile("s_waitcnt vmcnt(16)" ::: "memory");
            __syncthreads();                              // sync2
            if (tid == 0) {
                unsigned tgt = (unsigned)(s + 1);
                unsigned* fp = f0 + ub;
                asm volatile("global_store_dword %0, %1, off sc0 sc1"
                             :: "v"(fp), "v"(tgt) : "memory");
            }
            // 7) exit-only stores
            if (s == TT - 1) {
                int idx = b_e * 1024 + u_e;
                out[OUT_HL + idx] = hv;
                out[OUT_CL + idx] = cn;
            }
        }
    } else {
        for (int s = 1; s <= TT; ++s) {
            const int t1 = s - 1;
            f32x4 aE0 = {0,0,0,0}, aO0 = {0,0,0,0};
            f32x4 aE1 = {0,0,0,0}, aO1 = {0,0,0,0};
            bf16x8 bufA[8], bufB[8], bufC[8], bufD[8];
            // 1) concurrent pollers -> mailboxes (no barrier)
            if (w == 0) {
                POLL128(f0, (unsigned)s);
                if (lane == 0) MBX_SET(0, s);
            }
            if (w == 4) {
                if (s >= 2) POLL128(f1, (unsigned)s);
                if (lane == 0) MBX_SET(1, s);
            }
            // 2) spin own-slab mailbox (LDS; kh0 released by f0, kh1 by f1)
            MBX_SPIN(kh, s);
            // 3) ingest own slab + MFMA (kh0: hs0F[s]; kh1: ring[t1-1])
            {
                const ushort* a = (kh == 0)
                    ? hs0F + (size_t)s * SLAB + fro
                    : (t1 == 0 ? h1s0 + fro
                               : (const ushort*)Wt + (size_t)(t1 - 1) * SLAB + fro);
                ISSUE(bufA, a);
                ISSUE(bufB, a + 4096);
                ISSUE(bufC, a + 8192);
                ISSUE(bufD, a + 12288);
                CHUNK(bufA, kh * 32,      24, aE0, aE1);
                CHUNK(bufB, kh * 32 + 8,  16, aO0, aO1);
                CHUNK(bufC, kh * 32 + 16,  8, aE0, aE1);
                CHUNK(bufD, kh * 32 + 24,  0, aO0, aO1);
            }
            // 4) merge partials
            {
                const int cc = lane & 15, r0 = (lane >> 4) * 4;
#pragma unroll
                for (int r = 0; r < 4; ++r) {
                    gt[kh][m][0][r0 + r][cc] = aE0[r] + aO0[r];
                    gt[kh][m][1][r0 + r][cc] = aE1[r] + aO1[r];
                }
            }
            __syncthreads();                              // sync1
            // 5) balanced cell epilogue
            float g4[4];
#pragma unroll
            for (int g = 0; g < 4; ++g)
                g4[g] = gt[0][mb][ntb][blb][cpb + g] + gt[1][mb][ntb][blb][cpb + g] + cg[g];
            float si = sigf(g4[0]), sf = sigf(g4[1]), so = sigf(g4[3]);
            float cn = sf * creg + si * (2.f * sigf(2.f * g4[2]) - 1.f);
            float hv = so * (2.f * sigf(2.f * cn) - 1.f);
            creg = cn;
            uint hb = (uint)f2bf(hv);
            uint p0 = __shfl(hb, (lane & 56) + 0), p1 = __shfl(hb, (lane & 56) + 1);
            uint p2 = __shfl(hb, (lane & 56) + 2), p3 = __shfl(hb, (lane & 56) + 3);
            uint p4 = __shfl(hb, (lane & 56) + 4), p5 = __shfl(hb, (lane & 56) + 5);
            uint p6 = __shfl(hb, (lane & 56) + 6), p7 = __shfl(hb, (lane & 56) + 7);
            u32x4 hp;
            hp.x = (p0 & 0xffffu) | (p1 << 16);
            hp.y = (p2 & 0xffffu) | (p3 << 16);
            hp.z = (p4 & 0xffffu) | (p5 << 16);
            hp.w = (p6 & 0xffffu) | (p7 << 16);
            ushort* hdst = Wt + (size_t)t1 * SLAB + hoffL;   // ring slot t1
            if (u_off == 0)
                asm volatile("global_store_dwordx4 %0, %1, off sc0 sc1"
                             :: "v"(hdst), "v"(hp) : "memory");
            // 6) drain + sync + signal
            asm volatile("s_waitcnt vmcnt(0)" ::: "memory");
            __syncthreads();                              // sync2
            if (tid == 0) {
                unsigned tgt = (unsigned)(s + 1);
                unsigned* fp = f1 + ub;
                asm volatile("global_store_dword %0, %1, off sc0 sc1"
                             :: "v"(fp), "v"(tgt) : "memory");
            }
            // 7) output rows (exit-only data; overlaps next iteration)
            {
                float o0 = __shfl(hv, (lane & 56) + 0), o1 = __shfl(hv, (lane & 56) + 1);
                float o2 = __shfl(hv, (lane & 56) + 2), o3 = __shfl(hv, (lane & 56) + 3);
                float o4 = __shfl(hv, (lane & 56) + 4), o5 = __shfl(hv, (lane & 56) + 5);
                float o6 = __shfl(hv, (lane & 56) + 6), o7 = __shfl(hv, (lane & 56) + 7);
                if (u_off == 0) {
                    float* op = out + (size_t)t1 * BH + (size_t)b_e * 1024 + u0g;
                    float4 v0 = {o0, o1, o2, o3}, v1 = {o4, o5, o6, o7};
                    *(float4*)op = v0;
                    *(float4*)(op + 4) = v1;
                }
                if (t1 == TT - 1) {
                    int idx = b_e * 1024 + u_e;
                    out[OUT_HL + BH + idx] = hv;
                    out[OUT_CL + BH + idx] = cn;
                }
            }
        }
    }
}

extern "C" void kernel_launch(void* const* d_in, const int* in_sizes, int n_in,
                              void* d_out, int out_size, void* d_ws, size_t ws_size,
                              hipStream_t stream) {
    const float* attn = (const float*)d_in[0];
    const float* x    = (const float*)d_in[1];
    const float* h0   = (const float*)d_in[3];
    const float* c0   = (const float*)d_in[4];
    const float* wah  = (const float*)d_in[5];
    const float* wih  = (const float*)d_in[6];
    const float* whh  = (const float*)d_in[7];
    const float* bah  = (const float*)d_in[8];
    const float* bih  = (const float*)d_in[9];
    const float* bhh  = (const float*)d_in[10];
    float* out = (float*)d_out;

    char* ws = (char*)d_ws;
    ushort*   Wt     = (ushort*)(ws);               // [2][4096][2048] bf16 : 33,554,432
                                                    //   (reused as h1 ring, slots 0..255)
    ushort*   xbfF   = (ushort*)(ws + 33554432);    // frag-major x     : 33,554,432
    ushort*   hs0F   = (ushort*)(ws + 67108864);    // [257] slots      : 33,685,504
    ushort*   h1s0   = (ushort*)(ws + 100794368);   // h1 ring slot 0   : 131,072
    float*    constg = (float*)(ws + 100925440);    // [2][64][4096]    : 2,097,152
    unsigned* flags  = (unsigned*)(ws + 103022592); // [256] u32 (f0|f1)
    // total 103,023,616 B

    hipLaunchKernelGGL(k_prep_wt, dim3(32, 64, 2), dim3(256), 0, stream, wih, whh, Wt);
    hipLaunchKernelGGL(k_cast_x, dim3(8192), dim3(256), 0, stream, x, xbfF);
    hipLaunchKernelGGL(k_const, dim3(16, 8, 2), dim3(256), 0, stream, attn, wah, bah, bih, bhh, constg);
    hipLaunchKernelGGL(k_init, dim3(64), dim3(256), 0, stream, h0, hs0F, h1s0, flags);

    void* args[] = { (void*)&xbfF, (void*)&hs0F, (void*)&h1s0, (void*)&Wt,
                     (void*)&constg, (void*)&c0, (void*)&out, (void*)&flags };
    hipLaunchCooperativeKernel((void*)k_persist, dim3(NBLK), dim3(512), args, 0, stream);
}

// Round 16
// 1620.123 us; speedup vs baseline: 1.0314x; 1.0314x over previous
//
#include <hip/hip_runtime.h>
#include <hip/hip_bf16.h>
#include <stdint.h>

// Problem constants
#define TT 256
#define BH 65536        // B*H
#define B4H 262144      // B*4H
#define OUT_HL 16777216
#define OUT_CL (16777216 + 131072)
#define NBLK 256
#define SLAB 65536      // ushorts per [64][1024] bf16 activation slab

typedef __attribute__((ext_vector_type(8))) short bf16x8;
typedef __attribute__((ext_vector_type(4))) float f32x4;
typedef __attribute__((ext_vector_type(4))) unsigned int u32x4;
typedef __attribute__((ext_vector_type(2))) unsigned int u32x2;

__device__ __forceinline__ ushort f2bf(float v) {
    union { float f; uint32_t u; } x; x.f = v;
    uint32_t r = x.u + 0x7fff + ((x.u >> 16) & 1);
    return (ushort)(r >> 16);
}
__device__ __forceinline__ float sigf(float x) { return 1.f / (1.f + __expf(-x)); }

// Fragment-major layout for [64][1024] bf16 activation slabs:
//   off(b,k) = (b>>4)*16384 + (k>>5)*512 + ((k>>3)&3)*128 + (b&15)*8 + (k&7)
// A wave loading m-tile m, k-group ktg reads 64 lanes x 16B CONTIGUOUS 1KB.

// Build Wt[l][col'][k] bf16, col' = u*4+g for source column col=g*1024+u.
// sc stores: region is later reused as the layer-1 h ring (plain cached reads).
__global__ __launch_bounds__(256) void k_prep_wt(const float* __restrict__ wih,
                                                 const float* __restrict__ whh,
                                                 ushort* __restrict__ Wt) {
    __shared__ ushort tile[64][65];
    const int l = blockIdx.z;
    const int k0 = blockIdx.x * 64;
    const int col0 = blockIdx.y * 64;
    const int tid = threadIdx.x;
    const int cl = tid & 63, ks = tid >> 6;
    const float* src;
    int krow0;
    if (k0 < 1024) { src = wih + (size_t)l * 1024 * 4096; krow0 = k0; }
    else           { src = whh + (size_t)l * 1024 * 4096; krow0 = k0 - 1024; }
#pragma unroll
    for (int i = 0; i < 16; ++i) {
        int kl = ks + i * 4;
        tile[kl][cl] = f2bf(src[(size_t)(krow0 + kl) * 4096 + col0 + cl]);
    }
    __syncthreads();
    const int g0 = col0 >> 10, ub = col0 & 1023;
    ushort* dst = Wt + (size_t)l * 4096 * 2048;
    const int klane = tid & 63;
#pragma unroll
    for (int i = 0; i < 16; ++i) {
        int cl2 = (tid >> 6) + i * 4;
        int row = (ub + cl2) * 4 + g0;
        ushort* p = dst + (size_t)row * 2048 + k0 + klane;
        uint v = (uint)tile[klane][cl2];
        asm volatile("global_store_short %0, %1, off sc0 sc1"
                     :: "v"(p), "v"(v) : "memory");
    }
}

// x -> bf16 fragment-major xbfF[t][...]
__global__ __launch_bounds__(256) void k_cast_x(const float* __restrict__ x,
                                                ushort* __restrict__ xbfF) {
    int i = blockIdx.x * 256 + threadIdx.x;   // [256 t][64 b][128 k8]
    int k8 = i & 127, b = (i >> 7) & 63, t = i >> 13;
    const float4* xs = (const float4*)(x + (((size_t)t * 64 + b) * 1024 + k8 * 8));
    float4 a = xs[0], c = xs[1];
    uint4 pk;
    pk.x = (uint)f2bf(a.x) | ((uint)f2bf(a.y) << 16);
    pk.y = (uint)f2bf(a.z) | ((uint)f2bf(a.w) << 16);
    pk.z = (uint)f2bf(c.x) | ((uint)f2bf(c.y) << 16);
    pk.w = (uint)f2bf(c.z) | ((uint)f2bf(c.w) << 16);
    size_t off = (size_t)t * SLAB + (size_t)(b >> 4) * 16384 +
                 (size_t)(k8 >> 2) * 512 + (size_t)(k8 & 3) * 128 + (size_t)(b & 15) * 8;
    *(uint4*)(xbfF + off) = pk;
}

// const[l][b][col] = a0[b,:] @ W_ah[l][:,col] + bias_ah + bias_ih + bias_hh
__global__ __launch_bounds__(256) void k_const(const float* __restrict__ attn,
                                               const float* __restrict__ wah,
                                               const float* __restrict__ bah,
                                               const float* __restrict__ bih,
                                               const float* __restrict__ bhh,
                                               float* __restrict__ constg) {
    const int tid = threadIdx.x;
    const int col = blockIdx.x * 256 + tid;
    const int b0 = blockIdx.y * 8;
    const int l = blockIdx.z;
    const float* W = wah + (size_t)l * 512 * 4096;
    float acc[8] = {0.f, 0.f, 0.f, 0.f, 0.f, 0.f, 0.f, 0.f};
    for (int k = 0; k < 512; ++k) {
        float wv = W[(size_t)k * 4096 + col];
#pragma unroll
        for (int j = 0; j < 8; ++j) acc[j] += attn[(b0 + j) * 512 + k] * wv;
    }
    float bias = bah[l * 4096 + col] + bih[l * 4096 + col] + bhh[l * 4096 + col];
    float* cg = constg + (size_t)l * B4H;
#pragma unroll
    for (int j = 0; j < 8; ++j) cg[(size_t)(b0 + j) * 4096 + col] = acc[j] + bias;
}

// h0 -> fragment-major initial slabs; zero flags
__global__ __launch_bounds__(256) void k_init(const float* __restrict__ h0,
                                              ushort* __restrict__ hs0F,
                                              ushort* __restrict__ h1s0,
                                              unsigned* __restrict__ flags) {
    int i = blockIdx.x * 256 + threadIdx.x;   // [2 l][64 b][128 k8] = 16384
    if (i < 16384) {
        int k8 = i & 127, b = (i >> 7) & 63, l = i >> 13;
        const float* src = h0 + ((size_t)(l * 64 + b) * 1024 + k8 * 8);
        uint4 pk;
        pk.x = (uint)f2bf(src[0]) | ((uint)f2bf(src[1]) << 16);
        pk.y = (uint)f2bf(src[2]) | ((uint)f2bf(src[3]) << 16);
        pk.z = (uint)f2bf(src[4]) | ((uint)f2bf(src[5]) << 16);
        pk.w = (uint)f2bf(src[6]) | ((uint)f2bf(src[7]) << 16);
        size_t off = (size_t)(b >> 4) * 16384 + (size_t)(k8 >> 2) * 512 +
                     (size_t)(k8 & 3) * 128 + (size_t)(b & 15) * 8;
        *(uint4*)((l == 0 ? hs0F : h1s0) + off) = pk;
    }
    if (i < NBLK) flags[i] = 0u;
}

// ---- inline-asm helpers ----
#define ISSUE(BUF, BASE)                                                       \
    do { _Pragma("unroll")                                                     \
        for (int _i = 0; _i < 8; ++_i)                                         \
            asm volatile("global_load_dwordx4 %0, %1, off"                     \
                         : "=v"(BUF[_i]) : "v"((BASE) + _i * 512)); } while (0)

// Wait (N outstanding allowed), then 8 ktg x 2 nt = 16 MFMAs.
#define CHUNK(BUF, KTG0, N, A0, A1)                                            \
    do {                                                                       \
        asm volatile("s_waitcnt vmcnt(" #N ")" ::: "memory");                  \
        __builtin_amdgcn_sched_barrier(0x100);                                 \
        _Pragma("unroll")                                                      \
        for (int _i = 0; _i < 8; ++_i) {                                       \
            int _ktg = (KTG0) + _i;                                            \
            bf16x8 _b0 = *(const bf16x8*)(wlds + (size_t)_ktg * 1024 + lane * 8);       \
            bf16x8 _b1 = *(const bf16x8*)(wlds + (size_t)_ktg * 1024 + 512 + lane * 8); \
            A0 = __builtin_amdgcn_mfma_f32_16x16x32_bf16(BUF[_i], _b0, A0, 0, 0, 0);    \
            A1 = __builtin_amdgcn_mfma_f32_16x16x32_bf16(BUF[_i], _b1, A1, 0, 0, 0);    \
        }                                                                      \
    } while (0)

// 128-flag poll, single wave, 2 flags/lane. PIPELINED: two probes in flight;
// a probe's registers are only examined AFTER its counted vmcnt retires it
// (monotonic flags => checking a landed-but-stale value is safe/conservative).
#define POLL128(FB, TGT)                                                       \
    do {                                                                       \
        const unsigned* _fp = (FB) + lane * 2;                                 \
        u32x2 _fa, _fb;                                                        \
        asm volatile("global_load_dwordx2 %0, %1, off sc0 sc1"                 \
                     : "=v"(_fa) : "v"(_fp) : "memory");                       \
        while (true) {                                                         \
            asm volatile("global_load_dwordx2 %0, %1, off sc0 sc1"             \
                         : "=v"(_fb) : "v"(_fp) : "memory");                   \
            asm volatile("s_waitcnt vmcnt(1)" ::: "memory");  /* _fa landed */ \
            if (__all(_fa.x >= (TGT) && _fa.y >= (TGT))) {                     \
                asm volatile("s_waitcnt vmcnt(0)" ::: "memory");               \
                break;                                                         \
            }                                                                  \
            asm volatile("global_load_dwordx2 %0, %1, off sc0 sc1"             \
                         : "=v"(_fa) : "v"(_fp) : "memory");                   \
            asm volatile("s_waitcnt vmcnt(1)" ::: "memory");  /* _fb landed */ \
            if (__all(_fb.x >= (TGT) && _fb.y >= (TGT))) {                     \
                asm volatile("s_waitcnt vmcnt(0)" ::: "memory");               \
                break;                                                         \
            }                                                                  \
        }                                                                      \
    } while (0)

#define MBX_SET(I, V)                                                          \
    __hip_atomic_store(&mbx[I], (unsigned)(V), __ATOMIC_RELEASE,               \
                       __HIP_MEMORY_SCOPE_WORKGROUP)
#define MBX_SPIN(I, V)                                                         \
    while (__hip_atomic_load(&mbx[I], __ATOMIC_ACQUIRE,                        \
                             __HIP_MEMORY_SCOPE_WORKGROUP) < (unsigned)(V))    \
        __builtin_amdgcn_s_sleep(1)

// Persistent 2-layer LSTM, layer-split (r12-proven structure, 1572us).
// Blocks 0-127 = layer0 (8 units each), 128-255 = layer1.
// L0 iter s: x[s] MFMA from carried regs (drained: zero pre-poll stall, even
//   for the straggler block) -> poll f0>=s -> barrier -> issue h[s] + x[s+1]
//   -> h MFMA -> merge -> epilogue -> store hs0F[s+1] -> drain -> signal.
// L1 iter s (t=s-1): w0 polls f0 -> mbx0; w4 polls f1 -> mbx1 (CONCURRENT).
//   kh0 waves spin mbx0 then ingest hs0F[s]; kh1 waves spin mbx1 then ingest
//   ring[t-1]. merge -> epilogue -> ring[t] store -> drain -> signal -> out.
// Ring aliasing over Wt: slot t first written at iter t+1, gated by f0/f1
// chains proving all staging reads finished.
__global__ __launch_bounds__(512, 2) void k_persist(
        const ushort* __restrict__ xbfF,
        ushort* __restrict__ hs0F,
        const ushort* __restrict__ h1s0,
        ushort* Wt,                       // staging source + h1 ring (aliased)
        const float* __restrict__ constg,
        const float* __restrict__ c0,
        float* __restrict__ out,
        unsigned* __restrict__ flags) {
    __shared__ ushort wlds[65536];          // [64 ktg][2 nt][64 lane][8] = 128 KiB
    __shared__ float gt[2][4][2][16][18];   // [kh][m][nt][b&15][col'] 18 KiB
    __shared__ unsigned mbx[2];

    const int tid = threadIdx.x;
    const int w = tid >> 6, lane = tid & 63;
    const int kh = w >> 2, m = w & 3;
    const int bid = blockIdx.x;
    const int layer = bid >> 7, ub = bid & 127;
    const int u0g = ub * 8;

    // ---- stage this layer's 32 gate-cols x 2048 k into LDS (sc loads) ----
    {
        bf16x8 vst[16];
#pragma unroll
        for (int i = 0; i < 16; ++i) {
            int c = i * 512 + tid;
            int lp = c & 63, nt = (c >> 6) & 1, ktg = c >> 7;
            int colp = u0g * 4 + nt * 16 + (lp & 15);
            int kk = ktg * 32 + (lp >> 4) * 8;
            const ushort* src = Wt + ((size_t)(layer * 4096 + colp)) * 2048 + kk;
            asm volatile("global_load_dwordx4 %0, %1, off sc0 sc1"
                         : "=v"(vst[i]) : "v"(src));
        }
        asm volatile("s_waitcnt vmcnt(0)" ::: "memory");
        __builtin_amdgcn_sched_barrier(0);
#pragma unroll
        for (int i = 0; i < 16; ++i) {
            int c = i * 512 + tid;
            *(bf16x8*)(wlds + (size_t)c * 8) = vst[i];
        }
    }
    if (tid == 0) { mbx[0] = 0u; mbx[1] = 0u; }

    const int b_e = (w << 3) | (lane >> 3);
    const int u_off = lane & 7;
    const int u_e = u0g + u_off;
    float cg[4];
#pragma unroll
    for (int g = 0; g < 4; ++g)
        cg[g] = constg[(size_t)layer * B4H + (size_t)b_e * 4096 + g * 1024 + u_e];
    float creg = c0[layer * BH + b_e * 1024 + u_e];
    const int mb = b_e >> 4, blb = b_e & 15, ntb = u_off >> 2, cpb = (u_off & 3) * 4;
    const size_t hoffL = (size_t)mb * 16384 + (size_t)(ub >> 2) * 512 +
                         (size_t)(ub & 3) * 128 + (size_t)blb * 8;

    const size_t fro = (size_t)m * 16384 + (size_t)lane * 8;
    unsigned* f0 = flags;
    unsigned* f1 = flags + 128;

    __syncthreads();

    if (layer == 0) {
        bf16x8 bufXa[8], bufXb[8];
        // prologue: load x[0], complete (landed regs are safe to carry)
        {
            const ushort* ax = xbfF + fro + kh * 8192;
            ISSUE(bufXa, ax); ISSUE(bufXb, ax + 4096);
            asm volatile("s_waitcnt vmcnt(0)" ::: "memory");
            __builtin_amdgcn_sched_barrier(0);
        }
        for (int s = 0; s < TT; ++s) {
            f32x4 aE0 = {0,0,0,0}, aO0 = {0,0,0,0};
            f32x4 aE1 = {0,0,0,0}, aO1 = {0,0,0,0};
            bf16x8 bufHa[8], bufHb[8];
            // 1) x[s] MFMA from resident carried regs (vmcnt 0 outstanding)
            CHUNK(bufXa, kh * 16,     0, aE0, aE1);
            CHUNK(bufXb, kh * 16 + 8, 0, aO0, aO1);
            // 2) poll own-layer peers (their iter s-1) + release
            if (s >= 1 && w == 0) POLL128(f0, (unsigned)s);
            __syncthreads();
            // 3) h[s] ingest + x[s+1] issue + h MFMA
            {
                const ushort* ah = hs0F + (size_t)s * SLAB + fro + kh * 8192;
                ISSUE(bufHa, ah); ISSUE(bufHb, ah + 4096);          // 16 out
                const ushort* ax = xbfF + (size_t)((s + 1) & 255) * SLAB + fro + kh * 8192;
                ISSUE(bufXa, ax); ISSUE(bufXb, ax + 4096);          // 32 out
                CHUNK(bufHa, 32 + kh * 16,     24, aE0, aE1);       // first 8 h
                CHUNK(bufHb, 32 + kh * 16 + 8, 16, aO0, aO1);       // rest of h
            }
            // 4) merge partials
            {
                const int cc = lane & 15, r0 = (lane >> 4) * 4;
#pragma unroll
                for (int r = 0; r < 4; ++r) {
                    gt[kh][m][0][r0 + r][cc] = aE0[r] + aO0[r];
                    gt[kh][m][1][r0 + r][cc] = aE1[r] + aO1[r];
                }
            }
            __syncthreads();                              // sync1
            // 5) balanced cell epilogue
            float g4[4];
#pragma unroll
            for (int g = 0; g < 4; ++g)
                g4[g] = gt[0][mb][ntb][blb][cpb + g] + gt[1][mb][ntb][blb][cpb + g] + cg[g];
            float si = sigf(g4[0]), sf = sigf(g4[1]), so = sigf(g4[3]);
            float cn = sf * creg + si * (2.f * sigf(2.f * g4[2]) - 1.f);
            float hv = so * (2.f * sigf(2.f * cn) - 1.f);
            creg = cn;
            uint hb = (uint)f2bf(hv);
            uint p0 = __shfl(hb, (lane & 56) + 0), p1 = __shfl(hb, (lane & 56) + 1);
            uint p2 = __shfl(hb, (lane & 56) + 2), p3 = __shfl(hb, (lane & 56) + 3);
            uint p4 = __shfl(hb, (lane & 56) + 4), p5 = __shfl(hb, (lane & 56) + 5);
            uint p6 = __shfl(hb, (lane & 56) + 6), p7 = __shfl(hb, (lane & 56) + 7);
            u32x4 hp;
            hp.x = (p0 & 0xffffu) | (p1 << 16);
            hp.y = (p2 & 0xffffu) | (p3 << 16);
            hp.z = (p4 & 0xffffu) | (p5 << 16);
            hp.w = (p6 & 0xffffu) | (p7 << 16);
            ushort* hdst = hs0F + (size_t)(s + 1) * SLAB + hoffL;
            if (u_off == 0)
                asm volatile("global_store_dwordx4 %0, %1, off sc0 sc1"
                             :: "v"(hdst), "v"(hp) : "memory");
            // 6) drain (h-store + x[s+1] loads), sync, signal
            asm volatile("s_waitcnt vmcnt(0)" ::: "memory");
            __syncthreads();                              // sync2
            if (tid == 0) {
                unsigned tgt = (unsigned)(s + 1);
                unsigned* fp = f0 + ub;
                asm volatile("global_store_dword %0, %1, off sc0 sc1"
                             :: "v"(fp), "v"(tgt) : "memory");
            }
            // 7) exit-only stores
            if (s == TT - 1) {
                int idx = b_e * 1024 + u_e;
                out[OUT_HL + idx] = hv;
                out[OUT_CL + idx] = cn;
            }
        }
    } else {
        for (int s = 1; s <= TT; ++s) {
            const int t1 = s - 1;
            f32x4 aE0 = {0,0,0,0}, aO0 = {0,0,0,0};
            f32x4 aE1 = {0,0,0,0}, aO1 = {0,0,0,0};
            bf16x8 bufA[8], bufB[8], bufC[8], bufD[8];
            // 1) concurrent pollers -> mailboxes (no barrier)
            if (w == 0) {
                POLL128(f0, (unsigned)s);
                if (lane == 0) MBX_SET(0, s);
            }
            if (w == 4) {
                if (s >= 2) POLL128(f1, (unsigned)s);
                if (lane == 0) MBX_SET(1, s);
            }
            // 2) spin own-slab mailbox (LDS; kh0 released by f0, kh1 by f1)
            MBX_SPIN(kh, s);
            // 3) ingest own slab + MFMA (kh0: hs0F[s]; kh1: ring[t1-1])
            {
                const ushort* a = (kh == 0)
                    ? hs0F + (size_t)s * SLAB + fro
                    : (t1 == 0 ? h1s0 + fro
                               : (const ushort*)Wt + (size_t)(t1 - 1) * SLAB + fro);
                ISSUE(bufA, a);
                ISSUE(bufB, a + 4096);
                ISSUE(bufC, a + 8192);
                ISSUE(bufD, a + 12288);
                CHUNK(bufA, kh * 32,      24, aE0, aE1);
                CHUNK(bufB, kh * 32 + 8,  16, aO0, aO1);
                CHUNK(bufC, kh * 32 + 16,  8, aE0, aE1);
                CHUNK(bufD, kh * 32 + 24,  0, aO0, aO1);
            }
            // 4) merge partials
            {
                const int cc = lane & 15, r0 = (lane >> 4) * 4;
#pragma unroll
                for (int r = 0; r < 4; ++r) {
                    gt[kh][m][0][r0 + r][cc] = aE0[r] + aO0[r];
                    gt[kh][m][1][r0 + r][cc] = aE1[r] + aO1[r];
                }
            }
            __syncthreads();                              // sync1
            // 5) balanced cell epilogue
            float g4[4];
#pragma unroll
            for (int g = 0; g < 4; ++g)
                g4[g] = gt[0][mb][ntb][blb][cpb + g] + gt[1][mb][ntb][blb][cpb + g] + cg[g];
            float si = sigf(g4[0]), sf = sigf(g4[1]), so = sigf(g4[3]);
            float cn = sf * creg + si * (2.f * sigf(2.f * g4[2]) - 1.f);
            float hv = so * (2.f * sigf(2.f * cn) - 1.f);
            creg = cn;
            uint hb = (uint)f2bf(hv);
            uint p0 = __shfl(hb, (lane & 56) + 0), p1 = __shfl(hb, (lane & 56) + 1);
            uint p2 = __shfl(hb, (lane & 56) + 2), p3 = __shfl(hb, (lane & 56) + 3);
            uint p4 = __shfl(hb, (lane & 56) + 4), p5 = __shfl(hb, (lane & 56) + 5);
            uint p6 = __shfl(hb, (lane & 56) + 6), p7 = __shfl(hb, (lane & 56) + 7);
            u32x4 hp;
            hp.x = (p0 & 0xffffu) | (p1 << 16);
            hp.y = (p2 & 0xffffu) | (p3 << 16);
            hp.z = (p4 & 0xffffu) | (p5 << 16);
            hp.w = (p6 & 0xffffu) | (p7 << 16);
            ushort* hdst = Wt + (size_t)t1 * SLAB + hoffL;   // ring slot t1
            if (u_off == 0)
                asm volatile("global_store_dwordx4 %0, %1, off sc0 sc1"
                             :: "v"(hdst), "v"(hp) : "memory");
            // 6) drain + sync + signal
            asm volatile("s_waitcnt vmcnt(0)" ::: "memory");
            __syncthreads();                              // sync2
            if (tid == 0) {
                unsigned tgt = (unsigned)(s + 1);
                unsigned* fp = f1 + ub;
                asm volatile("global_store_dword %0, %1, off sc0 sc1"
                             :: "v"(fp), "v"(tgt) : "memory");
            }
            // 7) output rows (exit-only data; overlaps next iteration)
            {
                float o0 = __shfl(hv, (lane & 56) + 0), o1 = __shfl(hv, (lane & 56) + 1);
                float o2 = __shfl(hv, (lane & 56) + 2), o3 = __shfl(hv, (lane & 56) + 3);
                float o4 = __shfl(hv, (lane & 56) + 4), o5 = __shfl(hv, (lane & 56) + 5);
                float o6 = __shfl(hv, (lane & 56) + 6), o7 = __shfl(hv, (lane & 56) + 7);
                if (u_off == 0) {
                    float* op = out + (size_t)t1 * BH + (size_t)b_e * 1024 + u0g;
                    float4 v0 = {o0, o1, o2, o3}, v1 = {o4, o5, o6, o7};
                    *(float4*)op = v0;
                    *(float4*)(op + 4) = v1;
                }
                if (t1 == TT - 1) {
                    int idx = b_e * 1024 + u_e;
                    out[OUT_HL + BH + idx] = hv;
                    out[OUT_CL + BH + idx] = cn;
                }
            }
        }
    }
}

extern "C" void kernel_launch(void* const* d_in, const int* in_sizes, int n_in,
                              void* d_out, int out_size, void* d_ws, size_t ws_size,
                              hipStream_t stream) {
    const float* attn = (const float*)d_in[0];
    const float* x    = (const float*)d_in[1];
    const float* h0   = (const float*)d_in[3];
    const float* c0   = (const float*)d_in[4];
    const float* wah  = (const float*)d_in[5];
    const float* wih  = (const float*)d_in[6];
    const float* whh  = (const float*)d_in[7];
    const float* bah  = (const float*)d_in[8];
    const float* bih  = (const float*)d_in[9];
    const float* bhh  = (const float*)d_in[10];
    float* out = (float*)d_out;

    char* ws = (char*)d_ws;
    ushort*   Wt     = (ushort*)(ws);               // [2][4096][2048] bf16 : 33,554,432
                                                    //   (reused as h1 ring, slots 0..255)
    ushort*   xbfF   = (ushort*)(ws + 33554432);    // frag-major x     : 33,554,432
    ushort*   hs0F   = (ushort*)(ws + 67108864);    // [257] slots      : 33,685,504
    ushort*   h1s0   = (ushort*)(ws + 100794368);   // h1 ring slot 0   : 131,072
    float*    constg = (float*)(ws + 100925440);    // [2][64][4096]    : 2,097,152
    unsigned* flags  = (unsigned*)(ws + 103022592); // [256] u32 (f0|f1)
    // total 103,023,616 B

    hipLaunchKernelGGL(k_prep_wt, dim3(32, 64, 2), dim3(256), 0, stream, wih, whh, Wt);
    hipLaunchKernelGGL(k_cast_x, dim3(8192), dim3(256), 0, stream, x, xbfF);
    hipLaunchKernelGGL(k_const, dim3(16, 8, 2), dim3(256), 0, stream, attn, wah, bah, bih, bhh, constg);
    hipLaunchKernelGGL(k_init, dim3(64), dim3(256), 0, stream, h0, hs0F, h1s0, flags);

    void* args[] = { (void*)&xbfF, (void*)&hs0F, (void*)&h1s0, (void*)&Wt,
                     (void*)&constg, (void*)&c0, (void*)&out, (void*)&flags };
    hipLaunchCooperativeKernel((void*)k_persist, dim3(NBLK), dim3(512), args, 0, stream);
}

// Round 17
// 1600.646 us; speedup vs baseline: 1.0440x; 1.0122x over previous
//
#include <hip/hip_runtime.h>
#include <hip/hip_bf16.h>
#include <stdint.h>

// Problem constants
#define TT 256
#define BH 65536        // B*H
#define B4H 262144      // B*4H
#define OUT_HL 16777216
#define OUT_CL (16777216 + 131072)
#define NBLK 256
#define SLAB 65536      // ushorts per [64][1024] bf16 activation slab

typedef __attribute__((ext_vector_type(8))) short bf16x8;
typedef __attribute__((ext_vector_type(4))) float f32x4;
typedef __attribute__((ext_vector_type(4))) unsigned int u32x4;
typedef __attribute__((ext_vector_type(2))) unsigned int u32x2;

__device__ __forceinline__ ushort f2bf(float v) {
    union { float f; uint32_t u; } x; x.f = v;
    uint32_t r = x.u + 0x7fff + ((x.u >> 16) & 1);
    return (ushort)(r >> 16);
}
__device__ __forceinline__ float sigf(float x) { return 1.f / (1.f + __expf(-x)); }

// Fragment-major layout for [64][1024] bf16 activation slabs:
//   off(b,k) = (b>>4)*16384 + (k>>5)*512 + ((k>>3)&3)*128 + (b&15)*8 + (k&7)
// A wave loading m-tile m, k-group ktg reads 64 lanes x 16B CONTIGUOUS 1KB.

// Build Wt[l][col'][k] bf16, col' = u*4+g for source column col=g*1024+u.
// sc stores: region is later reused as the layer-1 h ring (plain cached reads).
__global__ __launch_bounds__(256) void k_prep_wt(const float* __restrict__ wih,
                                                 const float* __restrict__ whh,
                                                 ushort* __restrict__ Wt) {
    __shared__ ushort tile[64][65];
    const int l = blockIdx.z;
    const int k0 = blockIdx.x * 64;
    const int col0 = blockIdx.y * 64;
    const int tid = threadIdx.x;
    const int cl = tid & 63, ks = tid >> 6;
    const float* src;
    int krow0;
    if (k0 < 1024) { src = wih + (size_t)l * 1024 * 4096; krow0 = k0; }
    else           { src = whh + (size_t)l * 1024 * 4096; krow0 = k0 - 1024; }
#pragma unroll
    for (int i = 0; i < 16; ++i) {
        int kl = ks + i * 4;
        tile[kl][cl] = f2bf(src[(size_t)(krow0 + kl) * 4096 + col0 + cl]);
    }
    __syncthreads();
    const int g0 = col0 >> 10, ub = col0 & 1023;
    ushort* dst = Wt + (size_t)l * 4096 * 2048;
    const int klane = tid & 63;
#pragma unroll
    for (int i = 0; i < 16; ++i) {
        int cl2 = (tid >> 6) + i * 4;
        int row = (ub + cl2) * 4 + g0;
        ushort* p = dst + (size_t)row * 2048 + k0 + klane;
        uint v = (uint)tile[klane][cl2];
        asm volatile("global_store_short %0, %1, off sc0 sc1"
                     :: "v"(p), "v"(v) : "memory");
    }
}

// x -> bf16 fragment-major xbfF[t][...]
__global__ __launch_bounds__(256) void k_cast_x(const float* __restrict__ x,
                                                ushort* __restrict__ xbfF) {
    int i = blockIdx.x * 256 + threadIdx.x;   // [256 t][64 b][128 k8]
    int k8 = i & 127, b = (i >> 7) & 63, t = i >> 13;
    const float4* xs = (const float4*)(x + (((size_t)t * 64 + b) * 1024 + k8 * 8));
    float4 a = xs[0], c = xs[1];
    uint4 pk;
    pk.x = (uint)f2bf(a.x) | ((uint)f2bf(a.y) << 16);
    pk.y = (uint)f2bf(a.z) | ((uint)f2bf(a.w) << 16);
    pk.z = (uint)f2bf(c.x) | ((uint)f2bf(c.y) << 16);
    pk.w = (uint)f2bf(c.z) | ((uint)f2bf(c.w) << 16);
    size_t off = (size_t)t * SLAB + (size_t)(b >> 4) * 16384 +
                 (size_t)(k8 >> 2) * 512 + (size_t)(k8 & 3) * 128 + (size_t)(b & 15) * 8;
    *(uint4*)(xbfF + off) = pk;
}

// const[l][b][col] = a0[b,:] @ W_ah[l][:,col] + bias_ah + bias_ih + bias_hh
__global__ __launch_bounds__(256) void k_const(const float* __restrict__ attn,
                                               const float* __restrict__ wah,
                                               const float* __restrict__ bah,
                                               const float* __restrict__ bih,
                                               const float* __restrict__ bhh,
                                               float* __restrict__ constg) {
    const int tid = threadIdx.x;
    const int col = blockIdx.x * 256 + tid;
    const int b0 = blockIdx.y * 8;
    const int l = blockIdx.z;
    const float* W = wah + (size_t)l * 512 * 4096;
    float acc[8] = {0.f, 0.f, 0.f, 0.f, 0.f, 0.f, 0.f, 0.f};
    for (int k = 0; k < 512; ++k) {
        float wv = W[(size_t)k * 4096 + col];
#pragma unroll
        for (int j = 0; j < 8; ++j) acc[j] += attn[(b0 + j) * 512 + k] * wv;
    }
    float bias = bah[l * 4096 + col] + bih[l * 4096 + col] + bhh[l * 4096 + col];
    float* cg = constg + (size_t)l * B4H;
#pragma unroll
    for (int j = 0; j < 8; ++j) cg[(size_t)(b0 + j) * 4096 + col] = acc[j] + bias;
}

// h0 -> fragment-major initial slabs; zero flags
__global__ __launch_bounds__(256) void k_init(const float* __restrict__ h0,
                                              ushort* __restrict__ hs0F,
                                              ushort* __restrict__ h1s0,
                                              unsigned* __restrict__ flags) {
    int i = blockIdx.x * 256 + threadIdx.x;   // [2 l][64 b][128 k8] = 16384
    if (i < 16384) {
        int k8 = i & 127, b = (i >> 7) & 63, l = i >> 13;
        const float* src = h0 + ((size_t)(l * 64 + b) * 1024 + k8 * 8);
        uint4 pk;
        pk.x = (uint)f2bf(src[0]) | ((uint)f2bf(src[1]) << 16);
        pk.y = (uint)f2bf(src[2]) | ((uint)f2bf(src[3]) << 16);
        pk.z = (uint)f2bf(src[4]) | ((uint)f2bf(src[5]) << 16);
        pk.w = (uint)f2bf(src[6]) | ((uint)f2bf(src[7]) << 16);
        size_t off = (size_t)(b >> 4) * 16384 + (size_t)(k8 >> 2) * 512 +
                     (size_t)(k8 & 3) * 128 + (size_t)(b & 15) * 8;
        *(uint4*)((l == 0 ? hs0F : h1s0) + off) = pk;
    }
    if (i < NBLK) flags[i] = 0u;
}

// ---- inline-asm helpers ----
#define ISSUE(BUF, BASE)                                                       \
    do { _Pragma("unroll")                                                     \
        for (int _i = 0; _i < 8; ++_i)                                         \
            asm volatile("global_load_dwordx4 %0, %1, off"                     \
                         : "=v"(BUF[_i]) : "v"((BASE) + _i * 512)); } while (0)

// Wait (N outstanding allowed), then 8 ktg x 2 nt = 16 MFMAs.
#define CHUNK(BUF, KTG0, N, A0, A1)                                            \
    do {                                                                       \
        asm volatile("s_waitcnt vmcnt(" #N ")" ::: "memory");                  \
        __builtin_amdgcn_sched_barrier(0x100);                                 \
        _Pragma("unroll")                                                      \
        for (int _i = 0; _i < 8; ++_i) {                                       \
            int _ktg = (KTG0) + _i;                                            \
            bf16x8 _b0 = *(const bf16x8*)(wlds + (size_t)_ktg * 1024 + lane * 8);       \
            bf16x8 _b1 = *(const bf16x8*)(wlds + (size_t)_ktg * 1024 + 512 + lane * 8); \
            A0 = __builtin_amdgcn_mfma_f32_16x16x32_bf16(BUF[_i], _b0, A0, 0, 0, 0);    \
            A1 = __builtin_amdgcn_mfma_f32_16x16x32_bf16(BUF[_i], _b1, A1, 0, 0, 0);    \
        }                                                                      \
    } while (0)

// 128-flag poll, single wave, 2 flags/lane.
#define POLL128(FB, TGT)                                                       \
    do {                                                                       \
        const unsigned* _fp = (FB) + lane * 2;                                 \
        while (true) {                                                         \
            u32x2 _f;                                                          \
            asm volatile("global_load_dwordx2 %0, %1, off sc0 sc1\n\t"         \
                         "s_waitcnt vmcnt(0)"                                  \
                         : "=v"(_f) : "v"(_fp) : "memory");                    \
            if (__all(_f.x >= (TGT) && _f.y >= (TGT))) break;                  \
            __builtin_amdgcn_s_sleep(1);                                       \
        }                                                                      \
    } while (0)

#define MBX_SET(I, V)                                                          \
    __hip_atomic_store(&mbx[I], (unsigned)(V), __ATOMIC_RELEASE,               \
                       __HIP_MEMORY_SCOPE_WORKGROUP)
#define MBX_SPIN(I, V)                                                         \
    while (__hip_atomic_load(&mbx[I], __ATOMIC_ACQUIRE,                        \
                             __HIP_MEMORY_SCOPE_WORKGROUP) < (unsigned)(V))    \
        __builtin_amdgcn_s_sleep(1)

// Persistent 2-layer LSTM, layer-split (proven r12 structure, 1572 us).
// Blocks 0-127 = layer0 (8 units each), 128-255 = layer1.
// L0 iter s: x[s] MFMA from carried regs (fully drained before the loop edge:
//   zero pre-poll stall even for the straggler block) -> poll f0>=s ->
//   barrier -> issue h[s] + x[s+1] -> h MFMA -> merge -> epilogue -> store
//   hs0F[s+1] -> drain -> signal f0=s+1.
// L1 iter s (t=s-1): w0 polls f0>=s -> mbx[0]=s; w4 polls f1>=s -> mbx[1]=s
//   (CONCURRENT, no barrier). kh0 waves spin mbx[0] then ingest hs0F[s];
//   kh1 waves spin mbx[1] then ingest ring[t-1]. merge -> epilogue -> ring[t]
//   store -> drain -> signal f1=s+1 -> out rows.
// gt races prevented by sync1 (before epilogue) + sync2 (before next iter).
// Ring aliasing over Wt: slot t first written at iter t+1, gated by f0/f1
// chains proving all staging reads finished.
__global__ __launch_bounds__(512, 2) void k_persist(
        const ushort* __restrict__ xbfF,
        ushort* __restrict__ hs0F,
        const ushort* __restrict__ h1s0,
        ushort* Wt,                       // staging source + h1 ring (aliased)
        const float* __restrict__ constg,
        const float* __restrict__ c0,
        float* __restrict__ out,
        unsigned* __restrict__ flags) {
    __shared__ ushort wlds[65536];          // [64 ktg][2 nt][64 lane][8] = 128 KiB
    __shared__ float gt[2][4][2][16][18];   // [kh][m][nt][b&15][col'] 18 KiB
    __shared__ unsigned mbx[2];             // per-slab release mailboxes

    const int tid = threadIdx.x;
    const int w = tid >> 6, lane = tid & 63;
    const int kh = w >> 2, m = w & 3;
    const int bid = blockIdx.x;
    const int layer = bid >> 7, ub = bid & 127;
    const int u0g = ub * 8;

    // ---- stage this layer's 32 gate-cols x 2048 k into LDS (sc loads) ----
    {
        bf16x8 vst[16];
#pragma unroll
        for (int i = 0; i < 16; ++i) {
            int c = i * 512 + tid;          // 0..8191 chunks of 16B
            int lp = c & 63, nt = (c >> 6) & 1, ktg = c >> 7;
            int colp = u0g * 4 + nt * 16 + (lp & 15);
            int kk = ktg * 32 + (lp >> 4) * 8;
            const ushort* src = Wt + ((size_t)(layer * 4096 + colp)) * 2048 + kk;
            asm volatile("global_load_dwordx4 %0, %1, off sc0 sc1"
                         : "=v"(vst[i]) : "v"(src));
        }
        asm volatile("s_waitcnt vmcnt(0)" ::: "memory");
        __builtin_amdgcn_sched_barrier(0);
#pragma unroll
        for (int i = 0; i < 16; ++i) {
            int c = i * 512 + tid;
            *(bf16x8*)(wlds + (size_t)c * 8) = vst[i];
        }
    }
    if (tid == 0) { mbx[0] = 0u; mbx[1] = 0u; }

    const int b_e = (w << 3) | (lane >> 3);
    const int u_off = lane & 7;
    const int u_e = u0g + u_off;
    float cg[4];
#pragma unroll
    for (int g = 0; g < 4; ++g)
        cg[g] = constg[(size_t)layer * B4H + (size_t)b_e * 4096 + g * 1024 + u_e];
    float creg = c0[layer * BH + b_e * 1024 + u_e];
    const int mb = b_e >> 4, blb = b_e & 15, ntb = u_off >> 2, cpb = (u_off & 3) * 4;
    const size_t hoffL = (size_t)mb * 16384 + (size_t)(ub >> 2) * 512 +
                         (size_t)(ub & 3) * 128 + (size_t)blb * 8;

    const size_t fro = (size_t)m * 16384 + (size_t)lane * 8;
    unsigned* f0 = flags;
    unsigned* f1 = flags + 128;

    __syncthreads();

    if (layer == 0) {
        bf16x8 bufXa[8], bufXb[8];
        // prologue: load x[0], complete (landed regs are safe to carry)
        {
            const ushort* ax = xbfF + fro + kh * 8192;
            ISSUE(bufXa, ax); ISSUE(bufXb, ax + 4096);
            asm volatile("s_waitcnt vmcnt(0)" ::: "memory");
            __builtin_amdgcn_sched_barrier(0);
        }
        for (int s = 0; s < TT; ++s) {
            f32x4 aE0 = {0,0,0,0}, aO0 = {0,0,0,0};
            f32x4 aE1 = {0,0,0,0}, aO1 = {0,0,0,0};
            bf16x8 bufHa[8], bufHb[8];
            // 1) x[s] MFMA from resident carried regs (vmcnt 0 outstanding)
            CHUNK(bufXa, kh * 16,     0, aE0, aE1);
            CHUNK(bufXb, kh * 16 + 8, 0, aO0, aO1);
            // 2) poll own-layer peers (their iter s-1) + release
            if (s >= 1 && w == 0) POLL128(f0, (unsigned)s);
            __syncthreads();
            // 3) h[s] ingest + x[s+1] issue + h MFMA
            {
                const ushort* ah = hs0F + (size_t)s * SLAB + fro + kh * 8192;
                ISSUE(bufHa, ah); ISSUE(bufHb, ah + 4096);          // 16 out
                const ushort* ax = xbfF + (size_t)((s + 1) & 255) * SLAB + fro + kh * 8192;
                ISSUE(bufXa, ax); ISSUE(bufXb, ax + 4096);          // 32 out
                CHUNK(bufHa, 32 + kh * 16,     24, aE0, aE1);       // first 8 h
                CHUNK(bufHb, 32 + kh * 16 + 8, 16, aO0, aO1);       // rest of h
            }
            // 4) merge partials
            {
                const int cc = lane & 15, r0 = (lane >> 4) * 4;
#pragma unroll
                for (int r = 0; r < 4; ++r) {
                    gt[kh][m][0][r0 + r][cc] = aE0[r] + aO0[r];
                    gt[kh][m][1][r0 + r][cc] = aE1[r] + aO1[r];
                }
            }
            __syncthreads();                              // sync1
            // 5) balanced cell epilogue
            float g4[4];
#pragma unroll
            for (int g = 0; g < 4; ++g)
                g4[g] = gt[0][mb][ntb][blb][cpb + g] + gt[1][mb][ntb][blb][cpb + g] + cg[g];
            float si = sigf(g4[0]), sf = sigf(g4[1]), so = sigf(g4[3]);
            float cn = sf * creg + si * (2.f * sigf(2.f * g4[2]) - 1.f);
            float hv = so * (2.f * sigf(2.f * cn) - 1.f);
            creg = cn;
            uint hb = (uint)f2bf(hv);
            uint p0 = __shfl(hb, (lane & 56) + 0), p1 = __shfl(hb, (lane & 56) + 1);
            uint p2 = __shfl(hb, (lane & 56) + 2), p3 = __shfl(hb, (lane & 56) + 3);
            uint p4 = __shfl(hb, (lane & 56) + 4), p5 = __shfl(hb, (lane & 56) + 5);
            uint p6 = __shfl(hb, (lane & 56) + 6), p7 = __shfl(hb, (lane & 56) + 7);
            u32x4 hp;
            hp.x = (p0 & 0xffffu) | (p1 << 16);
            hp.y = (p2 & 0xffffu) | (p3 << 16);
            hp.z = (p4 & 0xffffu) | (p5 << 16);
            hp.w = (p6 & 0xffffu) | (p7 << 16);
            ushort* hdst = hs0F + (size_t)(s + 1) * SLAB + hoffL;
            if (u_off == 0)
                asm volatile("global_store_dwordx4 %0, %1, off sc0 sc1"
                             :: "v"(hdst), "v"(hp) : "memory");
            // 6) drain (h-store + x[s+1] loads), sync, signal
            asm volatile("s_waitcnt vmcnt(0)" ::: "memory");
            __syncthreads();                              // sync2
            if (tid == 0) {
                unsigned tgt = (unsigned)(s + 1);
                unsigned* fp = f0 + ub;
                asm volatile("global_store_dword %0, %1, off sc0 sc1"
                             :: "v"(fp), "v"(tgt) : "memory");
            }
            // 7) exit-only stores
            if (s == TT - 1) {
                int idx = b_e * 1024 + u_e;
                out[OUT_HL + idx] = hv;
                out[OUT_CL + idx] = cn;
            }
        }
    } else {
        for (int s = 1; s <= TT; ++s) {
            const int t1 = s - 1;
            f32x4 aE0 = {0,0,0,0}, aO0 = {0,0,0,0};
            f32x4 aE1 = {0,0,0,0}, aO1 = {0,0,0,0};
            bf16x8 bufA[8], bufB[8], bufC[8], bufD[8];
            // 1) concurrent pollers -> mailboxes (no barrier)
            if (w == 0) {
                POLL128(f0, (unsigned)s);
                if (lane == 0) MBX_SET(0, s);
            }
            if (w == 4) {
                if (s >= 2) POLL128(f1, (unsigned)s);
                if (lane == 0) MBX_SET(1, s);
            }
            // 2) spin own-slab mailbox (LDS; kh0 released by f0, kh1 by f1)
            MBX_SPIN(kh, s);
            // 3) ingest own slab + MFMA (kh0: hs0F[s]; kh1: ring[t1-1])
            {
                const ushort* a = (kh == 0)
                    ? hs0F + (size_t)s * SLAB + fro
                    : (t1 == 0 ? h1s0 + fro
                               : (const ushort*)Wt + (size_t)(t1 - 1) * SLAB + fro);
                ISSUE(bufA, a);
                ISSUE(bufB, a + 4096);
                ISSUE(bufC, a + 8192);
                ISSUE(bufD, a + 12288);
                CHUNK(bufA, kh * 32,      24, aE0, aE1);
                CHUNK(bufB, kh * 32 + 8,  16, aO0, aO1);
                CHUNK(bufC, kh * 32 + 16,  8, aE0, aE1);
                CHUNK(bufD, kh * 32 + 24,  0, aO0, aO1);
            }
            // 4) merge partials
            {
                const int cc = lane & 15, r0 = (lane >> 4) * 4;
#pragma unroll
                for (int r = 0; r < 4; ++r) {
                    gt[kh][m][0][r0 + r][cc] = aE0[r] + aO0[r];
                    gt[kh][m][1][r0 + r][cc] = aE1[r] + aO1[r];
                }
            }
            __syncthreads();                              // sync1
            // 5) balanced cell epilogue
            float g4[4];
#pragma unroll
            for (int g = 0; g < 4; ++g)
                g4[g] = gt[0][mb][ntb][blb][cpb + g] + gt[1][mb][ntb][blb][cpb + g] + cg[g];
            float si = sigf(g4[0]), sf = sigf(g4[1]), so = sigf(g4[3]);
            float cn = sf * creg + si * (2.f * sigf(2.f * g4[2]) - 1.f);
            float hv = so * (2.f * sigf(2.f * cn) - 1.f);
            creg = cn;
            uint hb = (uint)f2bf(hv);
            uint p0 = __shfl(hb, (lane & 56) + 0), p1 = __shfl(hb, (lane & 56) + 1);
            uint p2 = __shfl(hb, (lane & 56) + 2), p3 = __shfl(hb, (lane & 56) + 3);
            uint p4 = __shfl(hb, (lane & 56) + 4), p5 = __shfl(hb, (lane & 56) + 5);
            uint p6 = __shfl(hb, (lane & 56) + 6), p7 = __shfl(hb, (lane & 56) + 7);
            u32x4 hp;
            hp.x = (p0 & 0xffffu) | (p1 << 16);
            hp.y = (p2 & 0xffffu) | (p3 << 16);
            hp.z = (p4 & 0xffffu) | (p5 << 16);
            hp.w = (p6 & 0xffffu) | (p7 << 16);
            ushort* hdst = Wt + (size_t)t1 * SLAB + hoffL;   // ring slot t1
            if (u_off == 0)
                asm volatile("global_store_dwordx4 %0, %1, off sc0 sc1"
                             :: "v"(hdst), "v"(hp) : "memory");
            // 6) drain + sync + signal
            asm volatile("s_waitcnt vmcnt(0)" ::: "memory");
            __syncthreads();                              // sync2
            if (tid == 0) {
                unsigned tgt = (unsigned)(s + 1);
                unsigned* fp = f1 + ub;
                asm volatile("global_store_dword %0, %1, off sc0 sc1"
                             :: "v"(fp), "v"(tgt) : "memory");
            }
            // 7) output rows (exit-only data; overlaps next iteration)
            {
                float o0 = __shfl(hv, (lane & 56) + 0), o1 = __shfl(hv, (lane & 56) + 1);
                float o2 = __shfl(hv, (lane & 56) + 2), o3 = __shfl(hv, (lane & 56) + 3);
                float o4 = __shfl(hv, (lane & 56) + 4), o5 = __shfl(hv, (lane & 56) + 5);
                float o6 = __shfl(hv, (lane & 56) + 6), o7 = __shfl(hv, (lane & 56) + 7);
                if (u_off == 0) {
                    float* op = out + (size_t)t1 * BH + (size_t)b_e * 1024 + u0g;
                    float4 v0 = {o0, o1, o2, o3}, v1 = {o4, o5, o6, o7};
                    *(float4*)op = v0;
                    *(float4*)(op + 4) = v1;
                }
                if (t1 == TT - 1) {
                    int idx = b_e * 1024 + u_e;
                    out[OUT_HL + BH + idx] = hv;
                    out[OUT_CL + BH + idx] = cn;
                }
            }
        }
    }
}

extern "C" void kernel_launch(void* const* d_in, const int* in_sizes, int n_in,
                              void* d_out, int out_size, void* d_ws, size_t ws_size,
                              hipStream_t stream) {
    const float* attn = (const float*)d_in[0];
    const float* x    = (const float*)d_in[1];
    const float* h0   = (const float*)d_in[3];
    const float* c0   = (const float*)d_in[4];
    const float* wah  = (const float*)d_in[5];
    const float* wih  = (const float*)d_in[6];
    const float* whh  = (const float*)d_in[7];
    const float* bah  = (const float*)d_in[8];
    const float* bih  = (const float*)d_in[9];
    const float* bhh  = (const float*)d_in[10];
    float* out = (float*)d_out;

    char* ws = (char*)d_ws;
    ushort*   Wt     = (ushort*)(ws);               // [2][4096][2048] bf16 : 33,554,432
                                                    //   (reused as h1 ring, slots 0..255)
    ushort*   xbfF   = (ushort*)(ws + 33554432);    // frag-major x     : 33,554,432
    ushort*   hs0F   = (ushort*)(ws + 67108864);    // [257] slots      : 33,685,504
    ushort*   h1s0   = (ushort*)(ws + 100794368);   // h1 ring slot 0   : 131,072
    float*    constg = (float*)(ws + 100925440);    // [2][64][4096]    : 2,097,152
    unsigned* flags  = (unsigned*)(ws + 103022592); // [256] u32 (f0|f1)
    // total 103,023,616 B

    hipLaunchKernelGGL(k_prep_wt, dim3(32, 64, 2), dim3(256), 0, stream, wih, whh, Wt);
    hipLaunchKernelGGL(k_cast_x, dim3(8192), dim3(256), 0, stream, x, xbfF);
    hipLaunchKernelGGL(k_const, dim3(16, 8, 2), dim3(256), 0, stream, attn, wah, bah, bih, bhh, constg);
    hipLaunchKernelGGL(k_init, dim3(64), dim3(256), 0, stream, h0, hs0F, h1s0, flags);

    void* args[] = { (void*)&xbfF, (void*)&hs0F, (void*)&h1s0, (void*)&Wt,
                     (void*)&constg, (void*)&c0, (void*)&out, (void*)&flags };
    hipLaunchCooperativeKernel((void*)k_persist, dim3(NBLK), dim3(512), args, 0, stream);
}